// Round 2
// baseline (53614.679 us; speedup 1.0000x reference)
//
#include <hip/hip_runtime.h>

#define NPTS 8192
#define N2 (NPTS * 2)
#define TPB 256
#define NCH 32
#define CH (NPTS / NCH)         // 256 j per chunk
#define NITILE (NPTS / TPB)     // 32 i-tiles
#define NBLK3 (NITILE * NCH)    // 1024 matvec blocks
#define NBLK4 (N2 / TPB)        // 64 update blocks
#define T_ITERS 1792
#define NUG 1.0e-4
#define LAM 1.0e-5

typedef double2 dbl2;

__device__ __forceinline__ double block_reduce(double v, double* sred) {
  sred[threadIdx.x] = v;
  __syncthreads();
  for (int st = TPB >> 1; st >= 1; st >>= 1) {
    if ((int)threadIdx.x < st) sred[threadIdx.x] += sred[threadIdx.x + st];
    __syncthreads();
  }
  double res = sred[0];
  __syncthreads();
  return res;
}

// ---------------- setup: pack 4-d points, init CG state ----------------
extern "C" __global__ void __launch_bounds__(TPB)
k_setup(const float* __restrict__ Xmu, const float* __restrict__ Yeta,
        const float* __restrict__ Ymu, const float* __restrict__ Z,
        float* __restrict__ X4, float* __restrict__ M4, float* __restrict__ Y4,
        double* __restrict__ r, double* __restrict__ x,
        double* __restrict__ p0, double* __restrict__ p1,
        double* __restrict__ rrpart)
{
  int idx = blockIdx.x * TPB + threadIdx.x;   // 0..16383, (i,c)=(idx>>1, idx&1)
  int i = idx >> 1;
  float z = Z[idx];
  r[idx] = (double)z;
  x[idx] = 0.0;
  p0[idx] = 0.0;
  p1[idx] = 0.0;
  if ((idx & 1) == 0) {
    float a0 = Xmu[2 * i], a1 = Xmu[2 * i + 1];
    float e0 = Yeta[2 * i], e1 = Yeta[2 * i + 1];
    float m0 = Ymu[2 * i], m1 = Ymu[2 * i + 1];
    float z0 = Z[2 * i], z1 = Z[2 * i + 1];
    ((float4*)X4)[i] = make_float4(a0, a1, e0, e1);
    ((float4*)M4)[i] = make_float4(a0, a1, e0 + z0, e1 + z1);
    ((float4*)Y4)[i] = make_float4(a0, a1, m0, m1);
  }
  // rho_0 = <z,z> per column: parity-preserving block reduce
  __shared__ double sd[TPB];
  sd[threadIdx.x] = (double)z * (double)z;
  __syncthreads();
  for (int st = TPB >> 1; st >= 2; st >>= 1) {
    if ((int)threadIdx.x < st) sd[threadIdx.x] += sd[threadIdx.x + st];
    __syncthreads();
  }
  if (threadIdx.x < 2) rrpart[blockIdx.x * 2 + threadIdx.x] = sd[threadIdx.x];
}

// ---------------- MMD: three fused Gram sums ----------------
#define MCH 1024
extern "C" __global__ void __launch_bounds__(TPB)
k_mmd(const float* __restrict__ M4, const float* __restrict__ Y4,
      double* __restrict__ mmdpart)
{
  __shared__ float4 sM[MCH];
  __shared__ float4 sY[MCH];
  __shared__ double sred[TPB];
  int blk = blockIdx.x;            // 256 = 32 itiles x 8 chunks
  int itile = blk >> 3;
  int ch = blk & 7;
  int j0 = ch * MCH;
  for (int u = threadIdx.x; u < MCH; u += TPB) {
    sM[u] = ((const float4*)M4)[j0 + u];
    sY[u] = ((const float4*)Y4)[j0 + u];
  }
  __syncthreads();
  int i = itile * TPB + threadIdx.x;
  float4 mi = ((const float4*)M4)[i];
  float4 yi = ((const float4*)Y4)[i];
  double szz = 0.0, szy = 0.0, syy = 0.0;
  for (int jj = 0; jj < MCH; ++jj) {
    float4 mj = sM[jj];
    float4 yj = sY[jj];
    float d0 = mi.x - mj.x, d1 = mi.y - mj.y;     // shared X_mu part
    float a = fmaf(d1, d1, d0 * d0);
    float u0 = mi.z - mj.z, u1 = mi.w - mj.w;
    float v0 = mi.z - yj.z, v1 = mi.w - yj.w;
    float w0 = yi.z - yj.z, w1 = yi.w - yj.w;
    float dzz = fmaf(u0, u0, fmaf(u1, u1, a));
    float dzy = fmaf(v0, v0, fmaf(v1, v1, a));
    float dyy = fmaf(w0, w0, fmaf(w1, w1, a));
    szz += (double)__expf(-0.5f * dzz);
    szy += (double)__expf(-0.5f * dzy);
    syy += (double)__expf(-0.5f * dyy);
  }
  double S;
  S = block_reduce(szz, sred); if (threadIdx.x == 0) mmdpart[blk * 3 + 0] = S;
  S = block_reduce(szy, sred); if (threadIdx.x == 0) mmdpart[blk * 3 + 1] = S;
  S = block_reduce(syy, sred); if (threadIdx.x == 0) mmdpart[blk * 3 + 2] = S;
}

// ---------------- CG matvec with fused p-update + <p,q> partials ----------------
// p_t = r_t + beta_t * p_{t-1} computed during LDS staging (f32 copy for the
// matvec); owner chunk (ch==0) writes p_t in f64. q-partials per chunk (f32);
// <p,q> partials per block (f64).
extern "C" __global__ void __launch_bounds__(TPB)
k_matvec(const float* __restrict__ X4,
         const double* __restrict__ r, const double* __restrict__ pold,
         double* __restrict__ pnew, float* __restrict__ qpart,
         double* __restrict__ pqpart, const double* __restrict__ rrpart, int t)
{
  __shared__ float4 sx[CH];
  __shared__ float2 sp[CH];
  __shared__ double s1[128], s2[128];
  __shared__ double sred[TPB];
  __shared__ double beta[2];
  int blk = blockIdx.x;
  int itile = blk >> 5;     // /NCH
  int ch = blk & (NCH - 1);
  int j0 = ch * CH;

  if (t == 0) {
    if (threadIdx.x < 2) beta[threadIdx.x] = 0.0;
    __syncthreads();
  } else {
    const double* cur = rrpart + (t & 1) * 128;        // rho_t partials
    const double* prv = rrpart + ((t - 1) & 1) * 128;  // rho_{t-1} partials
    if (threadIdx.x < 128) { s1[threadIdx.x] = cur[threadIdx.x]; s2[threadIdx.x] = prv[threadIdx.x]; }
    __syncthreads();
    for (int st = 64; st >= 2; st >>= 1) {
      if ((int)threadIdx.x < st) { s1[threadIdx.x] += s1[threadIdx.x + st]; s2[threadIdx.x] += s2[threadIdx.x + st]; }
      __syncthreads();
    }
    if (threadIdx.x < 2) beta[threadIdx.x] = s1[threadIdx.x] / s2[threadIdx.x];
    __syncthreads();
  }

  double b0 = beta[0], b1 = beta[1];
  for (int u = threadIdx.x; u < CH; u += TPB) {
    sx[u] = ((const float4*)X4)[j0 + u];
    dbl2 rj = ((const dbl2*)r)[j0 + u];
    dbl2 pj = ((const dbl2*)pold)[j0 + u];
    sp[u] = make_float2((float)fma(b0, pj.x, rj.x), (float)fma(b1, pj.y, rj.y));
  }
  __syncthreads();

  int i = itile * TPB + threadIdx.x;
  float4 xi = ((const float4*)X4)[i];
  float q0 = 0.0f, q1 = 0.0f;
#pragma unroll 4
  for (int jj = 0; jj < CH; ++jj) {
    float4 cj = sx[jj];
    float2 pj = sp[jj];
    float d0 = xi.x - cj.x, d1 = xi.y - cj.y, d2 = xi.z - cj.z, d3 = xi.w - cj.w;
    float dd = fmaf(d3, d3, fmaf(d2, d2, fmaf(d1, d1, d0 * d0)));
    float e = __expf(-0.5f * dd);
    q0 = fmaf(e, pj.x, q0);
    q1 = fmaf(e, pj.y, q1);
  }
  ((float2*)qpart)[(size_t)ch * NPTS + i] = make_float2(q0, q1);

  dbl2 ri = ((const dbl2*)r)[i];
  dbl2 pi = ((const dbl2*)pold)[i];
  double pn0 = fma(b0, pi.x, ri.x);
  double pn1 = fma(b1, pi.y, ri.y);
  double t0 = pn0 * (double)q0, t1 = pn1 * (double)q1;  // partial <p, K p>
  if (ch == 0) {
    t0 = fma(NUG * pn0, pn0, t0);        // + eta <p,p> added exactly once
    t1 = fma(NUG * pn1, pn1, t1);
    ((dbl2*)pnew)[i] = make_double2(pn0, pn1);
  }
  double R;
  R = block_reduce(t0, sred); if (threadIdx.x == 0) pqpart[blk * 2 + 0] = R;
  R = block_reduce(t1, sred); if (threadIdx.x == 0) pqpart[blk * 2 + 1] = R;
}

// ---------------- CG update: reduce q, alpha, update x/r, rho partials ----------------
extern "C" __global__ void __launch_bounds__(TPB)
k_update(const float* __restrict__ qpart, const double* __restrict__ pnew,
         double* __restrict__ x, double* __restrict__ r,
         const double* __restrict__ pqpart, double* __restrict__ rrpart, int t)
{
  __shared__ double s1[TPB];
  __shared__ double s2[128];
  __shared__ double alpha[2];
  {
    double a = 0.0;
#pragma unroll
    for (int k = 0; k < 2 * NBLK3 / TPB; ++k)           // 8 chunks of 256
      a += pqpart[threadIdx.x + k * TPB];
    s1[threadIdx.x] = a;
    if (threadIdx.x < 128) s2[threadIdx.x] = rrpart[(t & 1) * 128 + threadIdx.x];
    __syncthreads();
    for (int st = 128; st >= 2; st >>= 1) {
      if ((int)threadIdx.x < st) s1[threadIdx.x] += s1[threadIdx.x + st];
      if (st <= 64 && (int)threadIdx.x < st) s2[threadIdx.x] += s2[threadIdx.x + st];
      __syncthreads();
    }
    if (threadIdx.x < 2) alpha[threadIdx.x] = s2[threadIdx.x] / s1[threadIdx.x];
    __syncthreads();
  }
  int idx = blockIdx.x * TPB + threadIdx.x;
  double pn = pnew[idx];
  double q = 0.0;
#pragma unroll
  for (int c = 0; c < NCH; ++c) q += (double)qpart[(size_t)c * N2 + idx];
  q = fma((double)NUG, pn, q);
  double a = alpha[idx & 1];
  double xv = fma(a, pn, x[idx]);
  double rv = fma(-a, q, r[idx]);
  x[idx] = xv;
  r[idx] = rv;
  s1[threadIdx.x] = rv * rv;
  __syncthreads();
  for (int st = 128; st >= 2; st >>= 1) {
    if ((int)threadIdx.x < st) s1[threadIdx.x] += s1[threadIdx.x + st];
    __syncthreads();
  }
  if (threadIdx.x < 2)
    rrpart[((t + 1) & 1) * 128 + blockIdx.x * 2 + threadIdx.x] = s1[threadIdx.x];
}

// ---------------- final combine ----------------
extern "C" __global__ void __launch_bounds__(TPB)
k_final(const float* __restrict__ Z, const double* __restrict__ x,
        const double* __restrict__ mmdpart, float* __restrict__ out)
{
  __shared__ double sred[TPB];
  double zx = 0.0;
  for (int idx = threadIdx.x; idx < N2; idx += TPB)
    zx += (double)Z[idx] * x[idx];
  double m0 = mmdpart[threadIdx.x * 3 + 0];
  double m1 = mmdpart[threadIdx.x * 3 + 1];
  double m2 = mmdpart[threadIdx.x * 3 + 2];
  double ZX = block_reduce(zx, sred);
  double S0 = block_reduce(m0, sred);
  double S1 = block_reduce(m1, sred);
  double S2 = block_reduce(m2, sred);
  if (threadIdx.x == 0) {
    double nn = (double)NPTS * (double)NPTS;
    double mmd = (S0 - 2.0 * S1 + S2) / nn;
    out[0] = (float)(mmd + LAM * ZX);
  }
}

extern "C" void kernel_launch(void* const* d_in, const int* in_sizes, int n_in,
                              void* d_out, int out_size, void* d_ws, size_t ws_size,
                              hipStream_t stream)
{
  (void)in_sizes; (void)n_in; (void)out_size; (void)ws_size;
  const float* Xmu  = (const float*)d_in[0];
  const float* Yeta = (const float*)d_in[1];
  const float* Ymu  = (const float*)d_in[2];
  const float* Z    = (const float*)d_in[3];
  float* out = (float*)d_out;

  char* w = (char*)d_ws;
  float*  X4      = (float*)(w);                         // 128 KB
  float*  M4      = (float*)(w + (128 << 10));           // 128 KB
  float*  Y4      = (float*)(w + (256 << 10));           // 128 KB
  double* r       = (double*)(w + (384 << 10));          // 128 KB
  double* x       = (double*)(w + (512 << 10));          // 128 KB
  double* pb0     = (double*)(w + (640 << 10));          // 128 KB
  double* pb1     = (double*)(w + (768 << 10));          // 128 KB
  float*  qpart   = (float*)(w + (896 << 10));           // 2 MB (NCH x N x 2 f32)
  double* pqpart  = (double*)(w + (2944 << 10));         // 16 KB (1024 blk x 2)
  double* rrpart  = (double*)(w + (2960 << 10));         // 2 KB
  double* mmdpart = (double*)(w + (2962 << 10));         // 6 KB

  hipLaunchKernelGGL(k_setup, dim3(NBLK4), dim3(TPB), 0, stream,
                     Xmu, Yeta, Ymu, Z, X4, M4, Y4, r, x, pb0, pb1, rrpart);
  hipLaunchKernelGGL(k_mmd, dim3(256), dim3(TPB), 0, stream, M4, Y4, mmdpart);
  for (int t = 0; t < T_ITERS; ++t) {
    double* po = (t & 1) ? pb1 : pb0;
    double* pn = (t & 1) ? pb0 : pb1;
    hipLaunchKernelGGL(k_matvec, dim3(NBLK3), dim3(TPB), 0, stream,
                       X4, r, po, pn, qpart, pqpart, rrpart, t);
    hipLaunchKernelGGL(k_update, dim3(NBLK4), dim3(TPB), 0, stream,
                       qpart, pn, x, r, pqpart, rrpart, t);
  }
  hipLaunchKernelGGL(k_final, dim3(1), dim3(TPB), 0, stream, Z, x, mmdpart, out);
}

// Round 3
// 32280.371 us; speedup vs baseline: 1.6609x; 1.6609x over previous
//
#include <hip/hip_runtime.h>

#define NPTS 8192
#define N2 (NPTS * 2)
#define TPB 256
#define NCH 32
#define CH (NPTS / NCH)         // 256 j per chunk
#define IB 2
#define ITILE (TPB * IB)        // 512 i per block
#define NITILE (NPTS / ITILE)   // 16 i-tiles
#define NBLK3 (NITILE * NCH)    // 512 matvec blocks
#define NBLK4 (N2 / TPB)        // 64 update blocks
#define T_ITERS 1152
#define NUG 1.0e-4
#define LAM 1.0e-5

typedef double2 dbl2;

__device__ __forceinline__ double block_reduce(double v, double* sred) {
  sred[threadIdx.x] = v;
  __syncthreads();
  for (int st = TPB >> 1; st >= 1; st >>= 1) {
    if ((int)threadIdx.x < st) sred[threadIdx.x] += sred[threadIdx.x + st];
    __syncthreads();
  }
  double res = sred[0];
  __syncthreads();
  return res;
}

// ---------------- setup: pack scaled 4-d points + norms, init CG state ----------------
// u = x / sqrt(2)  =>  |u_i - u_j|^2 = 0.5 |x_i - x_j|^2 ; K_ij = exp(-|u_i-u_j|^2)
extern "C" __global__ void __launch_bounds__(TPB)
k_setup(const float* __restrict__ Xmu, const float* __restrict__ Yeta,
        const float* __restrict__ Ymu, const float* __restrict__ Z,
        float* __restrict__ U4, float* __restrict__ UN,
        float* __restrict__ M4, float* __restrict__ Y4,
        double* __restrict__ r, double* __restrict__ x,
        double* __restrict__ p0, double* __restrict__ p1,
        double* __restrict__ rrpart)
{
  const float c = 0.70710678118654752f;
  int idx = blockIdx.x * TPB + threadIdx.x;   // 0..16383, (i,col)=(idx>>1, idx&1)
  int i = idx >> 1;
  float z = Z[idx];
  r[idx] = (double)z;
  x[idx] = 0.0;
  p0[idx] = 0.0;
  p1[idx] = 0.0;
  if ((idx & 1) == 0) {
    float a0 = Xmu[2 * i], a1 = Xmu[2 * i + 1];
    float e0 = Yeta[2 * i], e1 = Yeta[2 * i + 1];
    float m0 = Ymu[2 * i], m1 = Ymu[2 * i + 1];
    float z0 = Z[2 * i], z1 = Z[2 * i + 1];
    float u0 = c * a0, u1 = c * a1, u2 = c * e0, u3 = c * e1;
    ((float4*)U4)[i] = make_float4(u0, u1, u2, u3);
    UN[i] = fmaf(u3, u3, fmaf(u2, u2, fmaf(u1, u1, u0 * u0)));
    ((float4*)M4)[i] = make_float4(a0, a1, e0 + z0, e1 + z1);
    ((float4*)Y4)[i] = make_float4(a0, a1, m0, m1);
  }
  // rho_0 = <z,z> per column: parity-preserving block reduce
  __shared__ double sd[TPB];
  sd[threadIdx.x] = (double)z * (double)z;
  __syncthreads();
  for (int st = TPB >> 1; st >= 2; st >>= 1) {
    if ((int)threadIdx.x < st) sd[threadIdx.x] += sd[threadIdx.x + st];
    __syncthreads();
  }
  if (threadIdx.x < 2) rrpart[blockIdx.x * 2 + threadIdx.x] = sd[threadIdx.x];
}

// ---------------- MMD: three fused Gram sums ----------------
#define MCH 1024
extern "C" __global__ void __launch_bounds__(TPB)
k_mmd(const float* __restrict__ M4, const float* __restrict__ Y4,
      double* __restrict__ mmdpart)
{
  __shared__ float4 sM[MCH];
  __shared__ float4 sY[MCH];
  __shared__ double sred[TPB];
  int blk = blockIdx.x;            // 256 = 32 itiles x 8 chunks
  int itile = blk >> 3;
  int ch = blk & 7;
  int j0 = ch * MCH;
  for (int u = threadIdx.x; u < MCH; u += TPB) {
    sM[u] = ((const float4*)M4)[j0 + u];
    sY[u] = ((const float4*)Y4)[j0 + u];
  }
  __syncthreads();
  int i = itile * TPB + threadIdx.x;
  float4 mi = ((const float4*)M4)[i];
  float4 yi = ((const float4*)Y4)[i];
  double szz = 0.0, szy = 0.0, syy = 0.0;
  for (int jj = 0; jj < MCH; ++jj) {
    float4 mj = sM[jj];
    float4 yj = sY[jj];
    float d0 = mi.x - mj.x, d1 = mi.y - mj.y;     // shared X_mu part
    float a = fmaf(d1, d1, d0 * d0);
    float u0 = mi.z - mj.z, u1 = mi.w - mj.w;
    float v0 = mi.z - yj.z, v1 = mi.w - yj.w;
    float w0 = yi.z - yj.z, w1 = yi.w - yj.w;
    float dzz = fmaf(u0, u0, fmaf(u1, u1, a));
    float dzy = fmaf(v0, v0, fmaf(v1, v1, a));
    float dyy = fmaf(w0, w0, fmaf(w1, w1, a));
    szz += (double)__expf(-0.5f * dzz);
    szy += (double)__expf(-0.5f * dzy);
    syy += (double)__expf(-0.5f * dyy);
  }
  double S;
  S = block_reduce(szz, sred); if (threadIdx.x == 0) mmdpart[blk * 3 + 0] = S;
  S = block_reduce(szy, sred); if (threadIdx.x == 0) mmdpart[blk * 3 + 1] = S;
  S = block_reduce(syy, sred); if (threadIdx.x == 0) mmdpart[blk * 3 + 2] = S;
}

// ---------------- CG matvec: norm-trick distances, 2-way i blocking ----------------
// p_t = r_t + beta_t * p_{t-1} computed during LDS staging (f32 copy for the
// matvec); owner chunk (ch==0) writes p_t in f64. q-partials per chunk (f32);
// <p,q> partials per block (f64).
extern "C" __global__ void __launch_bounds__(TPB)
k_matvec(const float* __restrict__ U4, const float* __restrict__ UN,
         const double* __restrict__ r, const double* __restrict__ pold,
         double* __restrict__ pnew, float* __restrict__ qpart,
         double* __restrict__ pqpart, const double* __restrict__ rrpart, int t)
{
  __shared__ float4 sw[CH];     // 2 * u_j
  __shared__ float4 sa[CH];     // (n_j, p0_j, p1_j, 0)
  __shared__ double s1[128], s2[128];
  __shared__ double sred[TPB];
  __shared__ double beta[2];
  int blk = blockIdx.x;
  int itile = blk >> 5;         // / NCH
  int ch = blk & (NCH - 1);
  int j0 = ch * CH;

  if (t == 0) {
    if (threadIdx.x < 2) beta[threadIdx.x] = 0.0;
    __syncthreads();
  } else {
    const double* cur = rrpart + (t & 1) * 128;        // rho_t partials
    const double* prv = rrpart + ((t - 1) & 1) * 128;  // rho_{t-1} partials
    if (threadIdx.x < 128) { s1[threadIdx.x] = cur[threadIdx.x]; s2[threadIdx.x] = prv[threadIdx.x]; }
    __syncthreads();
    for (int st = 64; st >= 2; st >>= 1) {
      if ((int)threadIdx.x < st) { s1[threadIdx.x] += s1[threadIdx.x + st]; s2[threadIdx.x] += s2[threadIdx.x + st]; }
      __syncthreads();
    }
    if (threadIdx.x < 2) beta[threadIdx.x] = s1[threadIdx.x] / s2[threadIdx.x];
    __syncthreads();
  }

  double b0 = beta[0], b1 = beta[1];
  for (int u = threadIdx.x; u < CH; u += TPB) {
    float4 uj = ((const float4*)U4)[j0 + u];
    sw[u] = make_float4(2.f * uj.x, 2.f * uj.y, 2.f * uj.z, 2.f * uj.w);
    dbl2 rj = ((const dbl2*)r)[j0 + u];
    dbl2 pj = ((const dbl2*)pold)[j0 + u];
    sa[u] = make_float4(UN[j0 + u],
                        (float)fma(b0, pj.x, rj.x),
                        (float)fma(b1, pj.y, rj.y), 0.f);
  }
  __syncthreads();

  int i0 = itile * ITILE + threadIdx.x;
  int i1 = i0 + TPB;
  float4 ua = ((const float4*)U4)[i0];
  float4 ub = ((const float4*)U4)[i1];
  float na = UN[i0], nb = UN[i1];
  float qa0 = 0.f, qa1 = 0.f, qb0 = 0.f, qb1 = 0.f;
#pragma unroll 4
  for (int jj = 0; jj < CH; ++jj) {
    float4 w = sw[jj];
    float4 a = sa[jj];
    float ta = na + a.x;
    ta = fmaf(-ua.x, w.x, ta);
    ta = fmaf(-ua.y, w.y, ta);
    ta = fmaf(-ua.z, w.z, ta);
    ta = fmaf(-ua.w, w.w, ta);
    float ea = __expf(-ta);
    float tb = nb + a.x;
    tb = fmaf(-ub.x, w.x, tb);
    tb = fmaf(-ub.y, w.y, tb);
    tb = fmaf(-ub.z, w.z, tb);
    tb = fmaf(-ub.w, w.w, tb);
    float eb = __expf(-tb);
    qa0 = fmaf(ea, a.y, qa0);
    qa1 = fmaf(ea, a.z, qa1);
    qb0 = fmaf(eb, a.y, qb0);
    qb1 = fmaf(eb, a.z, qb1);
  }
  ((float2*)qpart)[(size_t)ch * NPTS + i0] = make_float2(qa0, qa1);
  ((float2*)qpart)[(size_t)ch * NPTS + i1] = make_float2(qb0, qb1);

  dbl2 ra = ((const dbl2*)r)[i0];
  dbl2 pa = ((const dbl2*)pold)[i0];
  dbl2 rb = ((const dbl2*)r)[i1];
  dbl2 pb = ((const dbl2*)pold)[i1];
  double pa0 = fma(b0, pa.x, ra.x);
  double pa1 = fma(b1, pa.y, ra.y);
  double pb0_ = fma(b0, pb.x, rb.x);
  double pb1_ = fma(b1, pb.y, rb.y);
  double t0 = pa0 * (double)qa0 + pb0_ * (double)qb0;   // partial <p, G p>
  double t1 = pa1 * (double)qa1 + pb1_ * (double)qb1;
  if (ch == 0) {
    t0 += NUG * (pa0 * pa0 + pb0_ * pb0_);              // + eta <p,p> once
    t1 += NUG * (pa1 * pa1 + pb1_ * pb1_);
    ((dbl2*)pnew)[i0] = make_double2(pa0, pa1);
    ((dbl2*)pnew)[i1] = make_double2(pb0_, pb1_);
  }
  double R;
  R = block_reduce(t0, sred); if (threadIdx.x == 0) pqpart[blk * 2 + 0] = R;
  R = block_reduce(t1, sred); if (threadIdx.x == 0) pqpart[blk * 2 + 1] = R;
}

// ---------------- CG update: reduce q, alpha, update x/r, rho partials ----------------
extern "C" __global__ void __launch_bounds__(TPB)
k_update(const float* __restrict__ qpart, const double* __restrict__ pnew,
         double* __restrict__ x, double* __restrict__ r,
         const double* __restrict__ pqpart, double* __restrict__ rrpart, int t)
{
  __shared__ double s1[TPB];
  __shared__ double s2[128];
  __shared__ double alpha[2];
  {
    double a = 0.0;
#pragma unroll
    for (int k = 0; k < 2 * NBLK3 / TPB; ++k)           // 4 chunks of 256
      a += pqpart[threadIdx.x + k * TPB];
    s1[threadIdx.x] = a;
    if (threadIdx.x < 128) s2[threadIdx.x] = rrpart[(t & 1) * 128 + threadIdx.x];
    __syncthreads();
    for (int st = 128; st >= 2; st >>= 1) {
      if ((int)threadIdx.x < st) s1[threadIdx.x] += s1[threadIdx.x + st];
      if (st <= 64 && (int)threadIdx.x < st) s2[threadIdx.x] += s2[threadIdx.x + st];
      __syncthreads();
    }
    if (threadIdx.x < 2) alpha[threadIdx.x] = s2[threadIdx.x] / s1[threadIdx.x];
    __syncthreads();
  }
  int idx = blockIdx.x * TPB + threadIdx.x;
  double pn = pnew[idx];
  double q = 0.0;
#pragma unroll
  for (int c = 0; c < NCH; ++c) q += (double)qpart[(size_t)c * N2 + idx];
  q = fma((double)NUG, pn, q);
  double a = alpha[idx & 1];
  double xv = fma(a, pn, x[idx]);
  double rv = fma(-a, q, r[idx]);
  x[idx] = xv;
  r[idx] = rv;
  s1[threadIdx.x] = rv * rv;
  __syncthreads();
  for (int st = 128; st >= 2; st >>= 1) {
    if ((int)threadIdx.x < st) s1[threadIdx.x] += s1[threadIdx.x + st];
    __syncthreads();
  }
  if (threadIdx.x < 2)
    rrpart[((t + 1) & 1) * 128 + blockIdx.x * 2 + threadIdx.x] = s1[threadIdx.x];
}

// ---------------- final combine ----------------
extern "C" __global__ void __launch_bounds__(TPB)
k_final(const float* __restrict__ Z, const double* __restrict__ x,
        const double* __restrict__ mmdpart, float* __restrict__ out)
{
  __shared__ double sred[TPB];
  double zx = 0.0;
  for (int idx = threadIdx.x; idx < N2; idx += TPB)
    zx += (double)Z[idx] * x[idx];
  double m0 = mmdpart[threadIdx.x * 3 + 0];
  double m1 = mmdpart[threadIdx.x * 3 + 1];
  double m2 = mmdpart[threadIdx.x * 3 + 2];
  double ZX = block_reduce(zx, sred);
  double S0 = block_reduce(m0, sred);
  double S1 = block_reduce(m1, sred);
  double S2 = block_reduce(m2, sred);
  if (threadIdx.x == 0) {
    double nn = (double)NPTS * (double)NPTS;
    double mmd = (S0 - 2.0 * S1 + S2) / nn;
    out[0] = (float)(mmd + LAM * ZX);
  }
}

extern "C" void kernel_launch(void* const* d_in, const int* in_sizes, int n_in,
                              void* d_out, int out_size, void* d_ws, size_t ws_size,
                              hipStream_t stream)
{
  (void)in_sizes; (void)n_in; (void)out_size; (void)ws_size;
  const float* Xmu  = (const float*)d_in[0];
  const float* Yeta = (const float*)d_in[1];
  const float* Ymu  = (const float*)d_in[2];
  const float* Z    = (const float*)d_in[3];
  float* out = (float*)d_out;

  char* w = (char*)d_ws;
  float*  U4      = (float*)(w);                         // 128 KB
  float*  UN      = (float*)(w + (128 << 10));           // 32 KB
  float*  M4      = (float*)(w + (160 << 10));           // 128 KB
  float*  Y4      = (float*)(w + (288 << 10));           // 128 KB
  double* r       = (double*)(w + (416 << 10));          // 128 KB
  double* x       = (double*)(w + (544 << 10));          // 128 KB
  double* pb0     = (double*)(w + (672 << 10));          // 128 KB
  double* pb1     = (double*)(w + (800 << 10));          // 128 KB
  float*  qpart   = (float*)(w + (928 << 10));           // 2 MB (NCH x N x 2 f32)
  double* pqpart  = (double*)(w + (2976 << 10));         // 8 KB (512 blk x 2)
  double* rrpart  = (double*)(w + (2984 << 10));         // 2 KB
  double* mmdpart = (double*)(w + (2986 << 10));         // 6 KB

  hipLaunchKernelGGL(k_setup, dim3(NBLK4), dim3(TPB), 0, stream,
                     Xmu, Yeta, Ymu, Z, U4, UN, M4, Y4, r, x, pb0, pb1, rrpart);
  hipLaunchKernelGGL(k_mmd, dim3(256), dim3(TPB), 0, stream, M4, Y4, mmdpart);
  for (int t = 0; t < T_ITERS; ++t) {
    double* po = (t & 1) ? pb1 : pb0;
    double* pn = (t & 1) ? pb0 : pb1;
    hipLaunchKernelGGL(k_matvec, dim3(NBLK3), dim3(TPB), 0, stream,
                       U4, UN, r, po, pn, qpart, pqpart, rrpart, t);
    hipLaunchKernelGGL(k_update, dim3(NBLK4), dim3(TPB), 0, stream,
                       qpart, pn, x, r, pqpart, rrpart, t);
  }
  hipLaunchKernelGGL(k_final, dim3(1), dim3(TPB), 0, stream, Z, x, mmdpart, out);
}